// Round 3
// baseline (644.663 us; speedup 1.0000x reference)
//
#include <hip/hip_runtime.h>

// Problem constants (fixed by setup_inputs)
#define BS   4
#define NH   8
#define SEQ  2048
#define DK   64
#define NP   129      // max_pos + 1
#define QP_PITCH 160  // qp scratch row pitch in floats: 640 B
#define PPAD 132      // proj LDS row pitch
#define RPB  2        // rows (b,i) per block in gather kernel

typedef float v4f __attribute__((ext_vector_type(4)));
typedef int   v4i __attribute__((ext_vector_type(4)));

// ---------------------------------------------------------------------------
// Kernel A: qp[r'][p] = dot(q_row(r'), w[p]),  r' = (b*SEQ + i)*NH + h
// Grid: 512 blocks x 256. Even/odd blocks do p in [0,64) / [64,129).
// phalf is block-derived so the w row address is wave-uniform (scalar loads).
// ---------------------------------------------------------------------------
__global__ __launch_bounds__(256) void proj_kernel(
    const float* __restrict__ q,   // [BS,NH,SEQ,DK]
    const float* __restrict__ w,   // [NP,DK]
    float*       __restrict__ qp)  // [BS*SEQ*NH, QP_PITCH]
{
    const int phalf = blockIdx.x & 1;
    const int rp    = ((blockIdx.x >> 1) << 8) + threadIdx.x;  // r' in [0,65536)
    const int h = rp & (NH - 1);
    const int i = (rp >> 3) & (SEQ - 1);
    const int b = rp >> 14;

    const float* qrow = q + (((size_t)(b * NH + h) * SEQ) + i) * DK;
    v4f qreg[16];
    #pragma unroll
    for (int k = 0; k < 16; ++k) qreg[k] = ((const v4f*)qrow)[k];

    float* orow = qp + (size_t)rp * QP_PITCH;
    const int p0 = phalf ? 64 : 0;

    for (int pq = 0; pq < 16; ++pq) {
        v4f acc;
        #pragma unroll
        for (int pp = 0; pp < 4; ++pp) {
            const int p = p0 + pq * 4 + pp;
            const v4f* wrow = (const v4f*)(w + p * DK);
            v4f s = {0.f, 0.f, 0.f, 0.f};
            #pragma unroll
            for (int k = 0; k < 16; ++k) s += qreg[k] * wrow[k];
            acc[pp] = s.x + s.y + s.z + s.w;
        }
        *(v4f*)(orow + p0 + pq * 4) = acc;
    }
    if (phalf) {  // tail position p = 128
        const v4f* wrow = (const v4f*)(w + 128 * DK);
        v4f s = {0.f, 0.f, 0.f, 0.f};
        #pragma unroll
        for (int k = 0; k < 16; ++k) s += qreg[k] * wrow[k];
        orow[128] = s.x + s.y + s.z + s.w;
    }
}

// ---------------------------------------------------------------------------
// Kernel B: one block per RPB adjacent (b,i) rows. Stage RPB*8 proj rows
// (8.4 KB LDS), gather by clamped dist, stream RPB*8 output rows with NT
// float4 stores. 128 KB stored per block amortizes dist-latency + barrier.
// ---------------------------------------------------------------------------
__global__ __launch_bounds__(256) void gather_kernel(
    const float* __restrict__ qp,    // [BS*SEQ*NH, QP_PITCH]
    const int*   __restrict__ dist,  // [BS,SEQ,SEQ]
    float*       __restrict__ out)   // [BS,NH,SEQ,SEQ]
{
    __shared__ __align__(16) float proj[RPB * NH * PPAD];  // 8448 B

    const int tid = threadIdx.x;
    const int bi0 = blockIdx.x << 1;     // first of 2 adjacent (b*SEQ+i) rows
    const int b   = bi0 >> 11;
    const int i0  = bi0 & (SEQ - 1);

    // Issue all dist loads early (2 rows x 2 chunks, rows contiguous)
    const v4i* dist4 = (const v4i*)(dist + (size_t)bi0 * SEQ);
    v4i dd[4];
    dd[0] = __builtin_nontemporal_load(&dist4[tid]);          // r0, it0
    dd[1] = __builtin_nontemporal_load(&dist4[256 + tid]);    // r0, it1
    dd[2] = __builtin_nontemporal_load(&dist4[512 + tid]);    // r1, it0
    dd[3] = __builtin_nontemporal_load(&dist4[768 + tid]);    // r1, it1

    // Stage 16 proj rows: qp rows bi0*NH .. bi0*NH+15 (contiguous).
    // 16 rows x 33 float4 = 528 slots.
    const float* qpb = qp + (size_t)bi0 * NH * QP_PITCH;
    for (int t = tid; t < RPB * NH * 33; t += 256) {
        const int row = t / 33;
        const int c   = t - row * 33;    // floats 4c..4c+3 (<=131 < QP_PITCH)
        const v4f v = __builtin_nontemporal_load(
            (const v4f*)(qpb + row * QP_PITCH + 4 * c));
        *(v4f*)&proj[row * PPAD + 4 * c] = v;
    }
    __syncthreads();

    // Gather + streamed stores: out[((b*NH+h)*SEQ + (i0+r))*SEQ + j]
    const size_t obase0 = ((size_t)(b * NH) * SEQ + i0) * SEQ;
    #pragma unroll
    for (int r = 0; r < RPB; ++r) {
        #pragma unroll
        for (int it = 0; it < 2; ++it) {
            const v4i d4 = dd[r * 2 + it];
            const int j0 = (it * 256 + tid) << 2;
            const int px = min(d4.x, NP - 1);
            const int py = min(d4.y, NP - 1);
            const int pz = min(d4.z, NP - 1);
            const int pw = min(d4.w, NP - 1);
            const size_t ob = obase0 + (size_t)r * SEQ + j0;
            #pragma unroll
            for (int h = 0; h < NH; ++h) {
                const float* pr = &proj[(r * NH + h) * PPAD];
                v4f v;
                v.x = pr[px];
                v.y = pr[py];
                v.z = pr[pz];
                v.w = pr[pw];
                __builtin_nontemporal_store(
                    v, (v4f*)(out + ob + (size_t)h * ((size_t)SEQ * SEQ)));
            }
        }
    }
}

extern "C" void kernel_launch(void* const* d_in, const int* in_sizes, int n_in,
                              void* d_out, int out_size, void* d_ws, size_t ws_size,
                              hipStream_t stream) {
    const float* q    = (const float*)d_in[0];
    const int*   dist = (const int*)d_in[1];
    const float* w    = (const float*)d_in[2];
    float*       out  = (float*)d_out;
    float*       qp   = (float*)d_ws;   // needs 65536 * 160 * 4 = 41.9 MB

    proj_kernel<<<512, 256, 0, stream>>>(q, w, qp);
    gather_kernel<<<(BS * SEQ) / RPB, 256, 0, stream>>>(qp, dist, out);
}